// Round 1
// baseline (496.255 us; speedup 1.0000x reference)
//
#include <hip/hip_runtime.h>

#define LVAL 2048
#define BVAL 4
#define KNB 30
#define NPOS 66
#define EDGE_IN 416
#define FPAD 424
#define NOUT 128

typedef __bf16 bf16x8 __attribute__((ext_vector_type(8)));
typedef float f32x4 __attribute__((ext_vector_type(4)));

__device__ __constant__ unsigned char c_PI[24] = {0,2,3,4,1,1,1,1,0,0,0,4,4,3,0,2,3,4,2,3,4,2,3,2};
__device__ __constant__ unsigned char c_PJ[24] = {0,2,3,4,0,2,3,4,2,3,4,2,3,2,1,1,1,1,0,0,0,4,4,3};

struct __align__(16) SMem {
  __bf16 feat[32 * FPAD];                 // 27136 B, A-operand tile (32 x 416, padded)
  unsigned long long selk[KNB];           // selected keys (distbits<<32 | idx), sorted
  unsigned long long smin[4];             // per-wave running min
  float smax[4];
  union {
    struct {
      float natoms[KNB * 5 * 3];          // neighbor atoms N,Ca,C,O,Cb
      float satoms[15];                   // self atoms
      float dpair[KNB * 24];              // 24 pair distances per edge
      float Dn[KNB];                      // D_neighbors
      int   dk[KNB];                      // positional bucket
    } p;
    float epre[KNB * 132];                // pre-LN GEMM output (stride 132)
  } u;
  float part[256];
  float mu[32];
  float rstd[32];
};

// distance exactly as numpy: ((dx*dx)+(dy*dy))+(dz*dz), +1e-6, IEEE sqrt, no FMA contraction
__device__ inline float ca_dist(float ax, float ay, float az, float bx, float by, float bz) {
#pragma clang fp contract(off)
  float dx = bx - ax, dy = by - ay, dz = bz - az;
  float d2 = ((dx * dx) + (dy * dy)) + (dz * dz);
  return sqrtf(d2 + 1e-6f);
}

__device__ inline unsigned long long wmin64(unsigned long long v) {
#pragma unroll
  for (int off = 32; off >= 1; off >>= 1) {
    unsigned long long o = __shfl_xor(v, off, 64);
    v = (o < v) ? o : v;
  }
  return v;
}

__device__ inline float wmaxf(float v) {
#pragma unroll
  for (int off = 32; off >= 1; off >>= 1) {
    float o = __shfl_xor(v, off, 64);
    v = fmaxf(v, o);
  }
  return v;
}

// compute atom a (0=N,1=Ca,2=C,3=O(slot4),4=Cb) of residue at row-base pointer
__device__ inline void get_atom(const float* __restrict__ base, int a, float& o0, float& o1, float& o2) {
  if (a < 3) {
    o0 = base[a * 3 + 0]; o1 = base[a * 3 + 1]; o2 = base[a * 3 + 2];
  } else if (a == 3) {
    o0 = base[12]; o1 = base[13]; o2 = base[14];
  } else {
    float nx = base[0], ny = base[1], nz = base[2];
    float ax = base[3], ay = base[4], az = base[5];
    float cx = base[6], cy = base[7], cz = base[8];
    float bvx = ax - nx, bvy = ay - ny, bvz = az - nz;
    float cvx = cx - ax, cvy = cy - ay, cvz = cz - az;
    float avx = bvy * cvz - bvz * cvy;
    float avy = bvz * cvx - bvx * cvz;
    float avz = bvx * cvy - bvy * cvx;
    o0 = (-0.58273431f * avx + 0.56802827f * bvx) - 0.54067466f * cvx + ax;
    o1 = (-0.58273431f * avy + 0.56802827f * bvy) - 0.54067466f * cvy + ay;
    o2 = (-0.58273431f * avz + 0.56802827f * bvz) - 0.54067466f * cvz + az;
  }
}

// pre-swizzle edge_W (128x416 fp32) into bf16 B-fragment order:
// frag element id = ((s*8 + nt)*64 + lane)*8 + jj ; k = 32s + (lane>>4)*8 + jj ; n = nt*16 + (lane&15)
__global__ void prep_w(const float* __restrict__ W, __bf16* __restrict__ wf) {
  int id = blockIdx.x * 256 + threadIdx.x;
  if (id >= 13 * 8 * 64 * 8) return;
  int jj = id & 7, l = (id >> 3) & 63, nt = (id >> 9) & 7, s = id >> 12;
  int k = 32 * s + ((l >> 4) << 3) + jj;
  int n = nt * 16 + (l & 15);
  wf[id] = (__bf16)W[n * EDGE_IN + k];
}

__global__ __launch_bounds__(256)
void pf_kernel(const float* __restrict__ X, const float* __restrict__ mask,
               const int* __restrict__ ridx, const int* __restrict__ chain,
               const float* __restrict__ posW, const float* __restrict__ posb,
               const float* __restrict__ lng, const float* __restrict__ lnb,
               const __bf16* __restrict__ wf,
               float* __restrict__ outE, float* __restrict__ outI) {
  __shared__ SMem sm;
  const int row = blockIdx.x;          // b*L + i
  const int b = row >> 11;
  const int tid = threadIdx.x;
  const int lane = tid & 63, wid = tid >> 6;

  // ---------------- phase 1: distances + top-30 (JAX tie-break) ----------------
  const float cax = X[(row * 5 + 1) * 3 + 0];
  const float cay = X[(row * 5 + 1) * 3 + 1];
  const float caz = X[(row * 5 + 1) * 3 + 2];
  const float mi = mask[row];

  float dval[8], m2v[8];
  float lmax = 0.f;
#pragma unroll
  for (int q = 0; q < 8; ++q) {
    int j = tid + 256 * q;
    const float* cj = X + ((b * LVAL + j) * 5 + 1) * 3;
    float m2 = mi * mask[b * LVAL + j];
    float D = m2 * ca_dist(cax, cay, caz, cj[0], cj[1], cj[2]);
    dval[q] = D; m2v[q] = m2;
    lmax = fmaxf(lmax, D);
  }
  {
    float wm = wmaxf(lmax);
    if (lane == 0) sm.smax[wid] = wm;
  }
  __syncthreads();
  const float Dmax = fmaxf(fmaxf(sm.smax[0], sm.smax[1]), fmaxf(sm.smax[2], sm.smax[3]));

  unsigned long long key[8];
  unsigned long long lmin = ~0ull;
#pragma unroll
  for (int q = 0; q < 8; ++q) {
    float Dadj = dval[q] + (1.0f - m2v[q]) * Dmax;
    unsigned long long kk = (((unsigned long long)__float_as_uint(Dadj)) << 32) | (unsigned)(tid + 256 * q);
    key[q] = kk;
    lmin = (kk < lmin) ? kk : lmin;
  }
  {
    unsigned long long v = wmin64(lmin);
    if (lane == 0) sm.smin[wid] = v;
  }
  __syncthreads();

  for (int r = 0; r < KNB; ++r) {
    unsigned long long w = sm.smin[0];
    w = (sm.smin[1] < w) ? sm.smin[1] : w;
    w = (sm.smin[2] < w) ? sm.smin[2] : w;
    w = (sm.smin[3] < w) ? sm.smin[3] : w;
    if (tid == 0) sm.selk[r] = w;
    bool iwin = (lmin == w);
    __syncthreads();
    if (__any(iwin)) {                    // only the winning wave re-reduces
      if (iwin) {
#pragma unroll
        for (int q = 0; q < 8; ++q) if (key[q] == w) key[q] = ~0ull;
        unsigned long long nm = key[0];
#pragma unroll
        for (int q = 1; q < 8; ++q) nm = (key[q] < nm) ? key[q] : nm;
        lmin = nm;
      }
      unsigned long long v = wmin64(lmin);
      if (lane == 0) sm.smin[wid] = v;
    }
    __syncthreads();
  }

  // ---------------- phase 2a: gather neighbor atoms / buckets ----------------
  if (tid < KNB * 5) {
    int k = tid / 5, a = tid - 5 * k;
    int j = (int)(sm.selk[k] & 0xffffffffull);
    const float* base = X + (size_t)(b * LVAL + j) * 15;
    float o0, o1, o2;
    get_atom(base, a, o0, o1, o2);
    sm.u.p.natoms[(k * 5 + a) * 3 + 0] = o0;
    sm.u.p.natoms[(k * 5 + a) * 3 + 1] = o1;
    sm.u.p.natoms[(k * 5 + a) * 3 + 2] = o2;
  } else if (tid < KNB * 5 + 5) {
    int a = tid - KNB * 5;
    const float* base = X + (size_t)row * 15;
    float o0, o1, o2;
    get_atom(base, a, o0, o1, o2);
    sm.u.p.satoms[a * 3 + 0] = o0;
    sm.u.p.satoms[a * 3 + 1] = o1;
    sm.u.p.satoms[a * 3 + 2] = o2;
  }
  if (tid < KNB) {
    unsigned long long k64 = sm.selk[tid];
    int j = (int)(k64 & 0xffffffffull);
    int off = ridx[row] - ridx[b * LVAL + j];
    int same = (chain[row] == chain[b * LVAL + j]) ? 1 : 0;
    int d = same ? min(max(off + 32, 0), 64) : 65;
    sm.u.p.dk[tid] = d;
    sm.u.p.Dn[tid] = __uint_as_float((unsigned)(k64 >> 32));
  }
  __syncthreads();

  // ---------------- phase 2b: 24 pair distances per edge ----------------
  for (int idx = tid; idx < KNB * 24; idx += 256) {
    int k = idx / 24, p = idx - 24 * k;
    const float* A = &sm.u.p.satoms[c_PI[p] * 3];
    const float* Bq = &sm.u.p.natoms[(k * 5 + c_PJ[p]) * 3];
    sm.u.p.dpair[idx] = ca_dist(A[0], A[1], A[2], Bq[0], Bq[1], Bq[2]);
  }
  __syncthreads();

  // ---------------- phase 2c: build 416-dim features (bf16, A-layout tile) ----------------
  for (int idx = tid; idx < KNB * EDGE_IN; idx += 256) {
    int k = idx / EDGE_IN, f = idx - EDGE_IN * k;
    float v;
    if (f < 16) {
      v = posW[f * NPOS + sm.u.p.dk[k]] + posb[f];
    } else {
      int r; float D;
      if (f < 32) { r = f - 16; D = sm.u.p.Dn[k]; }
      else { int ff = f - 32; int p = ff >> 4; r = ff & 15; D = sm.u.p.dpair[k * 24 + p]; }
      float t = (D - (2.0f + (4.0f / 3.0f) * (float)r)) * 0.8f;
      v = __expf(-(t * t));
    }
    sm.feat[k * FPAD + f] = (__bf16)v;
  }
  for (int idx = tid; idx < 2 * EDGE_IN; idx += 256) {  // zero pad rows 30,31
    int k2 = idx / EDGE_IN, f = idx - EDGE_IN * k2;
    sm.feat[(KNB + k2) * FPAD + f] = (__bf16)0.f;
  }
  __syncthreads();

  // ---------------- phase 3: MFMA GEMM  (32 x 416) @ (416 x 128) ----------------
  const int llo = lane & 15, lhi = lane >> 4;
  f32x4 acc00 = {0.f, 0.f, 0.f, 0.f}, acc01 = {0.f, 0.f, 0.f, 0.f};
  f32x4 acc10 = {0.f, 0.f, 0.f, 0.f}, acc11 = {0.f, 0.f, 0.f, 0.f};
  const __bf16* fbase0 = &sm.feat[llo * FPAD + lhi * 8];
  const __bf16* fbase1 = fbase0 + 16 * FPAD;
  const bf16x8* WFp = ((const bf16x8*)wf) + (2 * wid) * 64 + lane;
#pragma unroll
  for (int s = 0; s < 13; ++s) {
    bf16x8 a0 = *(const bf16x8*)(fbase0 + s * 32);
    bf16x8 a1 = *(const bf16x8*)(fbase1 + s * 32);
    bf16x8 b0 = WFp[s * 512];
    bf16x8 b1 = WFp[s * 512 + 64];
    acc00 = __builtin_amdgcn_mfma_f32_16x16x32_bf16(a0, b0, acc00, 0, 0, 0);
    acc01 = __builtin_amdgcn_mfma_f32_16x16x32_bf16(a0, b1, acc01, 0, 0, 0);
    acc10 = __builtin_amdgcn_mfma_f32_16x16x32_bf16(a1, b0, acc10, 0, 0, 0);
    acc11 = __builtin_amdgcn_mfma_f32_16x16x32_bf16(a1, b1, acc11, 0, 0, 0);
  }
  // epilogue: C/D layout col=lane&15, row=(lane>>4)*4+reg
  {
    int cb0 = (2 * wid) * 16 + llo, cb1 = cb0 + 16;
#pragma unroll
    for (int j = 0; j < 4; ++j) {
      int m0 = lhi * 4 + j;
      int m1 = 16 + m0;
      sm.u.epre[m0 * 132 + cb0] = acc00[j];
      sm.u.epre[m0 * 132 + cb1] = acc01[j];
      if (m1 < KNB) {
        sm.u.epre[m1 * 132 + cb0] = acc10[j];
        sm.u.epre[m1 * 132 + cb1] = acc11[j];
      }
    }
  }
  __syncthreads();

  // ---------------- phase 4: LayerNorm + write ----------------
  {
    int m = tid >> 3, sub = tid & 7;
    float s1 = 0.f;
    if (m < KNB) {
      const float* rp = &sm.u.epre[m * 132 + sub * 16];
#pragma unroll
      for (int c = 0; c < 16; ++c) s1 += rp[c];
    }
    sm.part[tid] = s1;
    __syncthreads();
    if (sub == 0 && m < KNB) {
      float s = 0.f;
#pragma unroll
      for (int q = 0; q < 8; ++q) s += sm.part[m * 8 + q];
      sm.mu[m] = s * (1.0f / 128.0f);
    }
    __syncthreads();
    float s2 = 0.f;
    if (m < KNB) {
      float mm = sm.mu[m];
      const float* rp = &sm.u.epre[m * 132 + sub * 16];
#pragma unroll
      for (int c = 0; c < 16; ++c) { float d = rp[c] - mm; s2 += d * d; }
    }
    sm.part[tid] = s2;
    __syncthreads();
    if (sub == 0 && m < KNB) {
      float s = 0.f;
#pragma unroll
      for (int q = 0; q < 8; ++q) s += sm.part[m * 8 + q];
      sm.rstd[m] = rsqrtf(s * (1.0f / 128.0f) + 1e-5f);
    }
    __syncthreads();
  }
  float* oE = outE + (size_t)row * KNB * NOUT;
  for (int idx = tid; idx < KNB * NOUT; idx += 256) {
    int m = idx >> 7, c = idx & 127;
    float v = (sm.u.epre[m * 132 + c] - sm.mu[m]) * sm.rstd[m] * lng[c] + lnb[c];
    oE[idx] = v;
  }
  if (tid < KNB)
    outI[(size_t)row * KNB + tid] = (float)(unsigned)(sm.selk[tid] & 0xffffffffull);
}

extern "C" void kernel_launch(void* const* d_in, const int* in_sizes, int n_in,
                              void* d_out, int out_size, void* d_ws, size_t ws_size,
                              hipStream_t stream) {
  const float* X = (const float*)d_in[0];
  const float* mask = (const float*)d_in[1];
  const int* ridx = (const int*)d_in[2];
  const int* chain = (const int*)d_in[3];
  const float* posW = (const float*)d_in[4];
  const float* posb = (const float*)d_in[5];
  const float* edgeW = (const float*)d_in[6];
  const float* lng = (const float*)d_in[7];
  const float* lnb = (const float*)d_in[8];
  float* outE = (float*)d_out;
  float* outI = outE + (size_t)BVAL * LVAL * KNB * NOUT;
  __bf16* wf = (__bf16*)d_ws;

  hipLaunchKernelGGL(prep_w, dim3(208), dim3(256), 0, stream, edgeW, wf);
  hipLaunchKernelGGL(pf_kernel, dim3(BVAL * LVAL), dim3(256), 0, stream,
                     X, mask, ridx, chain, posW, posb, lng, lnb, wf, outE, outI);
}

// Round 2
// 413.021 us; speedup vs baseline: 1.2015x; 1.2015x over previous
//
#include <hip/hip_runtime.h>

#define LVAL 2048
#define BVAL 4
#define KNB 30
#define NPOS 66
#define EDGE_IN 416
#define FPAD 424
#define NOUT 128

typedef __bf16 bf16x8 __attribute__((ext_vector_type(8)));
typedef float f32x4 __attribute__((ext_vector_type(4)));

__device__ __constant__ unsigned char c_PI[24] = {0,2,3,4,1,1,1,1,0,0,0,4,4,3,0,2,3,4,2,3,4,2,3,2};
__device__ __constant__ unsigned char c_PJ[24] = {0,2,3,4,0,2,3,4,2,3,4,2,3,2,1,1,1,1,0,0,0,4,4,3};

struct __align__(16) SMem {
  union {
    __bf16 feat[32 * FPAD];   // 27136 B: A-tile (32 x 416 padded), phases 2c-3
    float  epre[32 * 132];    // 16896 B: pre-LN GEMM out, epilogue..LN (after feat dead)
  } a;
  unsigned long long selk[KNB];       // global top-30 keys, sorted
  unsigned long long wcand[4 * KNB];  // per-wave top-30 lists (each sorted)
  float smax[4];
  struct {
    float natoms[KNB * 5 * 3];        // neighbor atoms N,Ca,C,O,Cb
    float satoms[15];                 // self atoms
    float dpair[KNB * 24];            // 24 pair distances per edge
    float Dn[KNB];                    // D_neighbors
    int   dk[KNB];                    // positional bucket
  } p;
};
// total ~33.4 KB -> 4 blocks/CU

// distance exactly as numpy: ((dx*dx)+(dy*dy))+(dz*dz), +1e-6, IEEE sqrt, no FMA contraction
__device__ inline float ca_dist(float ax, float ay, float az, float bx, float by, float bz) {
#pragma clang fp contract(off)
  float dx = bx - ax, dy = by - ay, dz = bz - az;
  float d2 = ((dx * dx) + (dy * dy)) + (dz * dz);
  return sqrtf(d2 + 1e-6f);
}

__device__ inline unsigned long long wmin64(unsigned long long v) {
#pragma unroll
  for (int off = 32; off >= 1; off >>= 1) {
    unsigned long long o = __shfl_xor(v, off, 64);
    v = (o < v) ? o : v;
  }
  return v;
}

__device__ inline float wmaxf(float v) {
#pragma unroll
  for (int off = 32; off >= 1; off >>= 1) {
    float o = __shfl_xor(v, off, 64);
    v = fmaxf(v, o);
  }
  return v;
}

// compute atom a (0=N,1=Ca,2=C,3=O(slot4),4=Cb) of residue at row-base pointer
__device__ inline void get_atom(const float* __restrict__ base, int a, float& o0, float& o1, float& o2) {
  if (a < 3) {
    o0 = base[a * 3 + 0]; o1 = base[a * 3 + 1]; o2 = base[a * 3 + 2];
  } else if (a == 3) {
    o0 = base[12]; o1 = base[13]; o2 = base[14];
  } else {
    float nx = base[0], ny = base[1], nz = base[2];
    float ax = base[3], ay = base[4], az = base[5];
    float cx = base[6], cy = base[7], cz = base[8];
    float bvx = ax - nx, bvy = ay - ny, bvz = az - nz;
    float cvx = cx - ax, cvy = cy - ay, cvz = cz - az;
    float avx = bvy * cvz - bvz * cvy;
    float avy = bvz * cvx - bvx * cvz;
    float avz = bvx * cvy - bvy * cvx;
    o0 = (-0.58273431f * avx + 0.56802827f * bvx) - 0.54067466f * cvx + ax;
    o1 = (-0.58273431f * avy + 0.56802827f * bvy) - 0.54067466f * cvy + ay;
    o2 = (-0.58273431f * avz + 0.56802827f * bvz) - 0.54067466f * cvz + az;
  }
}

// pre-swizzle edge_W (128x416 fp32) into bf16 B-fragment order:
// frag element id = ((s*8 + nt)*64 + lane)*8 + jj ; k = 32s + (lane>>4)*8 + jj ; n = nt*16 + (lane&15)
__global__ void prep_w(const float* __restrict__ W, __bf16* __restrict__ wf) {
  int id = blockIdx.x * 256 + threadIdx.x;
  if (id >= 13 * 8 * 64 * 8) return;
  int jj = id & 7, l = (id >> 3) & 63, nt = (id >> 9) & 7, s = id >> 12;
  int k = 32 * s + ((l >> 4) << 3) + jj;
  int n = nt * 16 + (l & 15);
  wf[id] = (__bf16)W[n * EDGE_IN + k];
}

__global__ __launch_bounds__(256, 4)
void pf_kernel(const float* __restrict__ X, const float* __restrict__ mask,
               const int* __restrict__ ridx, const int* __restrict__ chain,
               const float* __restrict__ posW, const float* __restrict__ posb,
               const float* __restrict__ lng, const float* __restrict__ lnb,
               const __bf16* __restrict__ wf,
               float* __restrict__ outE, float* __restrict__ outI) {
  __shared__ SMem sm;
  const int row = blockIdx.x;          // b*L + i
  const int b = row >> 11;
  const int tid = threadIdx.x;
  const int lane = tid & 63, wid = tid >> 6;

  // ---------------- phase 1: distances + per-wave top-30 (no barriers) ----------------
  const float cax = X[(row * 5 + 1) * 3 + 0];
  const float cay = X[(row * 5 + 1) * 3 + 1];
  const float caz = X[(row * 5 + 1) * 3 + 2];
  const float mi = mask[row];

  float dval[8], m2v[8];
  float lmax = 0.f;
#pragma unroll
  for (int q = 0; q < 8; ++q) {
    int j = (wid << 9) | (q << 6) | lane;     // wave wid owns j in [512*wid, 512*wid+512)
    const float* cj = X + ((b * LVAL + j) * 5 + 1) * 3;
    float m2 = mi * mask[b * LVAL + j];
    float D = m2 * ca_dist(cax, cay, caz, cj[0], cj[1], cj[2]);
    dval[q] = D; m2v[q] = m2;
    lmax = fmaxf(lmax, D);
  }
  {
    float wm = wmaxf(lmax);
    if (lane == 0) sm.smax[wid] = wm;
  }
  __syncthreads();
  const float Dmax = fmaxf(fmaxf(sm.smax[0], sm.smax[1]), fmaxf(sm.smax[2], sm.smax[3]));

  unsigned long long key[8];
  unsigned long long lmin = ~0ull;
#pragma unroll
  for (int q = 0; q < 8; ++q) {
    int j = (wid << 9) | (q << 6) | lane;
    float Dadj = dval[q] + (1.0f - m2v[q]) * Dmax;
    unsigned long long kk = (((unsigned long long)__float_as_uint(Dadj)) << 32) | (unsigned)j;
    key[q] = kk;
    lmin = (kk < lmin) ? kk : lmin;
  }

  // 30 extraction rounds, purely intra-wave (16 independent chains per CU hide latency)
  for (int r = 0; r < KNB; ++r) {
    unsigned long long w = wmin64(lmin);
    if (lane == 0) sm.wcand[wid * KNB + r] = w;
    if (lmin == w) {                     // unique winner lane (keys unique)
#pragma unroll
      for (int q = 0; q < 8; ++q) if (key[q] == w) key[q] = ~0ull;
      unsigned long long nm = key[0];
#pragma unroll
      for (int q = 1; q < 8; ++q) nm = (key[q] < nm) ? key[q] : nm;
      lmin = nm;
    }
  }
  __syncthreads();

  // rank merge: 4 sorted lists of 30 -> global sorted top-30 (keys unique => ranks unique)
  if (tid < 4 * KNB) {
    unsigned long long k = sm.wcand[tid];
    int rank = 0;
#pragma unroll 8
    for (int s = 0; s < 4 * KNB; ++s) rank += (int)(sm.wcand[s] < k);
    if (rank < KNB) sm.selk[rank] = k;
  }
  __syncthreads();

  // ---------------- phase 2a: gather neighbor atoms / buckets + write E_idx ----------------
  if (tid < KNB * 5) {
    int k = tid / 5, a = tid - 5 * k;
    int j = (int)(sm.selk[k] & 0xffffffffull);
    const float* base = X + (size_t)(b * LVAL + j) * 15;
    float o0, o1, o2;
    get_atom(base, a, o0, o1, o2);
    sm.p.natoms[(k * 5 + a) * 3 + 0] = o0;
    sm.p.natoms[(k * 5 + a) * 3 + 1] = o1;
    sm.p.natoms[(k * 5 + a) * 3 + 2] = o2;
  } else if (tid < KNB * 5 + 5) {
    int a = tid - KNB * 5;
    const float* base = X + (size_t)row * 15;
    float o0, o1, o2;
    get_atom(base, a, o0, o1, o2);
    sm.p.satoms[a * 3 + 0] = o0;
    sm.p.satoms[a * 3 + 1] = o1;
    sm.p.satoms[a * 3 + 2] = o2;
  }
  if (tid < KNB) {
    unsigned long long k64 = sm.selk[tid];
    int j = (int)(k64 & 0xffffffffull);
    int off = ridx[row] - ridx[b * LVAL + j];
    int same = (chain[row] == chain[b * LVAL + j]) ? 1 : 0;
    int d = same ? min(max(off + 32, 0), 64) : 65;
    sm.p.dk[tid] = d;
    sm.p.Dn[tid] = __uint_as_float((unsigned)(k64 >> 32));
    outI[(size_t)row * KNB + tid] = (float)(unsigned)j;
  }
  __syncthreads();

  // ---------------- phase 2b: 24 pair distances per edge ----------------
  for (int idx = tid; idx < KNB * 24; idx += 256) {
    int k = idx / 24, p = idx - 24 * k;
    const float* A = &sm.p.satoms[c_PI[p] * 3];
    const float* Bq = &sm.p.natoms[(k * 5 + c_PJ[p]) * 3];
    sm.p.dpair[idx] = ca_dist(A[0], A[1], A[2], Bq[0], Bq[1], Bq[2]);
  }
  __syncthreads();

  // ---------------- phase 2c: build 416-dim features (bf16, A-layout tile) ----------------
  for (int idx = tid; idx < KNB * EDGE_IN; idx += 256) {
    int k = idx / EDGE_IN, f = idx - EDGE_IN * k;
    float v;
    if (f < 16) {
      v = posW[f * NPOS + sm.p.dk[k]] + posb[f];
    } else {
      int r; float D;
      if (f < 32) { r = f - 16; D = sm.p.Dn[k]; }
      else { int ff = f - 32; int p = ff >> 4; r = ff & 15; D = sm.p.dpair[k * 24 + p]; }
      float t = (D - (2.0f + (4.0f / 3.0f) * (float)r)) * 0.8f;
      v = __expf(-(t * t));
    }
    sm.a.feat[k * FPAD + f] = (__bf16)v;
  }
  for (int idx = tid; idx < 2 * EDGE_IN; idx += 256) {  // zero pad rows 30,31
    int k2 = idx / EDGE_IN, f = idx - EDGE_IN * k2;
    sm.a.feat[(KNB + k2) * FPAD + f] = (__bf16)0.f;
  }
  __syncthreads();

  // ---------------- phase 3: MFMA GEMM  (32 x 416) @ (416 x 128) ----------------
  const int llo = lane & 15, lhi = lane >> 4;
  f32x4 acc00 = {0.f, 0.f, 0.f, 0.f}, acc01 = {0.f, 0.f, 0.f, 0.f};
  f32x4 acc10 = {0.f, 0.f, 0.f, 0.f}, acc11 = {0.f, 0.f, 0.f, 0.f};
  const __bf16* fbase0 = &sm.a.feat[llo * FPAD + lhi * 8];
  const __bf16* fbase1 = fbase0 + 16 * FPAD;
  const bf16x8* WFp = ((const bf16x8*)wf) + (2 * wid) * 64 + lane;
#pragma unroll
  for (int s = 0; s < 13; ++s) {
    bf16x8 a0 = *(const bf16x8*)(fbase0 + s * 32);
    bf16x8 a1 = *(const bf16x8*)(fbase1 + s * 32);
    bf16x8 b0 = WFp[s * 512];
    bf16x8 b1 = WFp[s * 512 + 64];
    acc00 = __builtin_amdgcn_mfma_f32_16x16x32_bf16(a0, b0, acc00, 0, 0, 0);
    acc01 = __builtin_amdgcn_mfma_f32_16x16x32_bf16(a0, b1, acc01, 0, 0, 0);
    acc10 = __builtin_amdgcn_mfma_f32_16x16x32_bf16(a1, b0, acc10, 0, 0, 0);
    acc11 = __builtin_amdgcn_mfma_f32_16x16x32_bf16(a1, b1, acc11, 0, 0, 0);
  }
  __syncthreads();   // feat (union w/ epre) must be fully read before epilogue writes
  // epilogue: C/D layout col=lane&15, row=(lane>>4)*4+reg ; rows 30,31 are zeros, kept
  {
    int cb0 = (2 * wid) * 16 + llo, cb1 = cb0 + 16;
#pragma unroll
    for (int j = 0; j < 4; ++j) {
      int m0 = lhi * 4 + j;
      int m1 = 16 + m0;
      sm.a.epre[m0 * 132 + cb0] = acc00[j];
      sm.a.epre[m0 * 132 + cb1] = acc01[j];
      sm.a.epre[m1 * 132 + cb0] = acc10[j];
      sm.a.epre[m1 * 132 + cb1] = acc11[j];
    }
  }
  __syncthreads();

  // ---------------- phase 4: LayerNorm via width-8 shuffles + fused store ----------------
  {
    int m = tid >> 3, sub = tid & 7;            // threads 8m..8m+7 own row m (same wave)
    const f32x4* rp = (const f32x4*)&sm.a.epre[m * 132 + sub * 16];
    f32x4 v0 = rp[0], v1 = rp[1], v2 = rp[2], v3 = rp[3];
    float s1 = ((v0[0] + v0[1]) + (v0[2] + v0[3])) + ((v1[0] + v1[1]) + (v1[2] + v1[3]))
             + ((v2[0] + v2[1]) + (v2[2] + v2[3])) + ((v3[0] + v3[1]) + (v3[2] + v3[3]));
    s1 += __shfl_xor(s1, 1, 64);
    s1 += __shfl_xor(s1, 2, 64);
    s1 += __shfl_xor(s1, 4, 64);
    float mu = s1 * (1.0f / 128.0f);
    float s2 = 0.f;
#pragma unroll
    for (int c = 0; c < 4; ++c) { float d = v0[c] - mu; s2 += d * d; }
#pragma unroll
    for (int c = 0; c < 4; ++c) { float d = v1[c] - mu; s2 += d * d; }
#pragma unroll
    for (int c = 0; c < 4; ++c) { float d = v2[c] - mu; s2 += d * d; }
#pragma unroll
    for (int c = 0; c < 4; ++c) { float d = v3[c] - mu; s2 += d * d; }
    s2 += __shfl_xor(s2, 1, 64);
    s2 += __shfl_xor(s2, 2, 64);
    s2 += __shfl_xor(s2, 4, 64);
    float rstd = rsqrtf(s2 * (1.0f / 128.0f) + 1e-5f);
    if (m < KNB) {
      const f32x4* gp = (const f32x4*)(lng + sub * 16);
      const f32x4* bp = (const f32x4*)(lnb + sub * 16);
      f32x4* op = (f32x4*)(outE + (size_t)row * KNB * NOUT + m * NOUT + sub * 16);
      f32x4 g0 = gp[0], g1 = gp[1], g2 = gp[2], g3 = gp[3];
      f32x4 b0 = bp[0], b1 = bp[1], b2 = bp[2], b3 = bp[3];
      f32x4 o0, o1, o2, o3;
#pragma unroll
      for (int c = 0; c < 4; ++c) o0[c] = (v0[c] - mu) * rstd * g0[c] + b0[c];
#pragma unroll
      for (int c = 0; c < 4; ++c) o1[c] = (v1[c] - mu) * rstd * g1[c] + b1[c];
#pragma unroll
      for (int c = 0; c < 4; ++c) o2[c] = (v2[c] - mu) * rstd * g2[c] + b2[c];
#pragma unroll
      for (int c = 0; c < 4; ++c) o3[c] = (v3[c] - mu) * rstd * g3[c] + b3[c];
      op[0] = o0; op[1] = o1; op[2] = o2; op[3] = o3;
    }
  }
}

extern "C" void kernel_launch(void* const* d_in, const int* in_sizes, int n_in,
                              void* d_out, int out_size, void* d_ws, size_t ws_size,
                              hipStream_t stream) {
  const float* X = (const float*)d_in[0];
  const float* mask = (const float*)d_in[1];
  const int* ridx = (const int*)d_in[2];
  const int* chain = (const int*)d_in[3];
  const float* posW = (const float*)d_in[4];
  const float* posb = (const float*)d_in[5];
  const float* edgeW = (const float*)d_in[6];
  const float* lng = (const float*)d_in[7];
  const float* lnb = (const float*)d_in[8];
  float* outE = (float*)d_out;
  float* outI = outE + (size_t)BVAL * LVAL * KNB * NOUT;
  __bf16* wf = (__bf16*)d_ws;

  hipLaunchKernelGGL(prep_w, dim3(208), dim3(256), 0, stream, edgeW, wf);
  hipLaunchKernelGGL(pf_kernel, dim3(BVAL * LVAL), dim3(256), 0, stream,
                     X, mask, ridx, chain, posW, posb, lng, lnb, wf, outE, outI);
}

// Round 3
// 257.843 us; speedup vs baseline: 1.9246x; 1.6018x over previous
//
#include <hip/hip_runtime.h>

#define LVAL 2048
#define BVAL 4
#define KNB 30
#define NPOS 66
#define EDGE_IN 416
#define FPAD 424
#define NOUT 128
#define CAP 128

typedef __bf16 bf16x8 __attribute__((ext_vector_type(8)));
typedef float f32x4 __attribute__((ext_vector_type(4)));

__device__ __constant__ unsigned char c_PI[24] = {0,2,3,4,1,1,1,1,0,0,0,4,4,3,0,2,3,4,2,3,4,2,3,2};
__device__ __constant__ unsigned char c_PJ[24] = {0,2,3,4,0,2,3,4,2,3,4,2,3,2,1,1,1,1,0,0,0,4,4,3};

struct __align__(16) SMem {
  union {
    __bf16 feat[32 * FPAD];   // 27136 B: A-tile (32 x 416 padded)
    float  epre[32 * 132];    // 16896 B: pre-LN GEMM out (after feat dead)
  } a;
  unsigned long long selk[KNB];       // global top-30 keys, sorted
  float smax[4];
  union {
    struct {                          // phase-1 radix-select scratch
      unsigned hist[256];
      unsigned wsum[4];
      unsigned T1, r0, Pthr, cnt;
      unsigned long long list[CAP];
    } s;
    struct {                          // phase-2 scratch
      float natoms[KNB * 5 * 3];      // neighbor atoms N,Ca,C,O,Cb
      float satoms[15];               // self atoms
      float Dn[KNB];                  // D_neighbors
      int   dk[KNB];                  // positional bucket
    } p;
  } u;
};
// total ~29.5 KB -> 5 blocks/CU

// distance exactly as numpy: ((dx*dx)+(dy*dy))+(dz*dz), +1e-6, IEEE sqrt, no FMA contraction
__device__ inline float ca_dist(float ax, float ay, float az, float bx, float by, float bz) {
#pragma clang fp contract(off)
  float dx = bx - ax, dy = by - ay, dz = bz - az;
  float d2 = ((dx * dx) + (dy * dy)) + (dz * dz);
  return sqrtf(d2 + 1e-6f);
}

__device__ inline float wmaxf(float v) {
#pragma unroll
  for (int off = 32; off >= 1; off >>= 1) {
    float o = __shfl_xor(v, off, 64);
    v = fmaxf(v, o);
  }
  return v;
}

// compute atom a (0=N,1=Ca,2=C,3=O(slot4),4=Cb) of residue at row-base pointer
__device__ inline void get_atom(const float* __restrict__ base, int a, float& o0, float& o1, float& o2) {
  if (a < 3) {
    o0 = base[a * 3 + 0]; o1 = base[a * 3 + 1]; o2 = base[a * 3 + 2];
  } else if (a == 3) {
    o0 = base[12]; o1 = base[13]; o2 = base[14];
  } else {
    float nx = base[0], ny = base[1], nz = base[2];
    float ax = base[3], ay = base[4], az = base[5];
    float cx = base[6], cy = base[7], cz = base[8];
    float bvx = ax - nx, bvy = ay - ny, bvz = az - nz;
    float cvx = cx - ax, cvy = cy - ay, cvz = cz - az;
    float avx = bvy * cvz - bvz * cvy;
    float avy = bvz * cvx - bvx * cvz;
    float avz = bvx * cvy - bvy * cvx;
    o0 = (-0.58273431f * avx + 0.56802827f * bvx) - 0.54067466f * cvx + ax;
    o1 = (-0.58273431f * avy + 0.56802827f * bvy) - 0.54067466f * cvy + ay;
    o2 = (-0.58273431f * avz + 0.56802827f * bvz) - 0.54067466f * cvz + az;
  }
}

// pre-swizzle edge_W (128x416 fp32) into bf16 B-fragment order:
// frag element id = ((s*8 + nt)*64 + lane)*8 + jj ; k = 32s + (lane>>4)*8 + jj ; n = nt*16 + (lane&15)
__global__ void prep_w(const float* __restrict__ W, __bf16* __restrict__ wf) {
  int id = blockIdx.x * 256 + threadIdx.x;
  if (id >= 13 * 8 * 64 * 8) return;
  int jj = id & 7, l = (id >> 3) & 63, nt = (id >> 9) & 7, s = id >> 12;
  int k = 32 * s + ((l >> 4) << 3) + jj;
  int n = nt * 16 + (l & 15);
  wf[id] = (__bf16)W[n * EDGE_IN + k];
}

__global__ __launch_bounds__(256, 5)
void pf_kernel(const float* __restrict__ X, const float* __restrict__ mask,
               const int* __restrict__ ridx, const int* __restrict__ chain,
               const float* __restrict__ posW, const float* __restrict__ posb,
               const float* __restrict__ lng, const float* __restrict__ lnb,
               const __bf16* __restrict__ wf,
               float* __restrict__ outE, float* __restrict__ outI) {
  __shared__ SMem sm;
  const int row = blockIdx.x;          // b*L + i
  const int b = row >> 11;
  const int tid = threadIdx.x;
  const int lane = tid & 63, wid = tid >> 6;

  // ---------------- phase 1: distances + 2-level radix-select top-30 ----------------
  sm.u.s.hist[tid] = 0;
  if (tid == 0) sm.u.s.cnt = 0;

  const float cax = X[(row * 5 + 1) * 3 + 0];
  const float cay = X[(row * 5 + 1) * 3 + 1];
  const float caz = X[(row * 5 + 1) * 3 + 2];
  const float mi = mask[row];

  float dval[8], m2v[8];
  float lmax = 0.f;
#pragma unroll
  for (int q = 0; q < 8; ++q) {
    int j = (wid << 9) | (q << 6) | lane;
    const float* cj = X + ((b * LVAL + j) * 5 + 1) * 3;
    float m2 = mi * mask[b * LVAL + j];
    float D = m2 * ca_dist(cax, cay, caz, cj[0], cj[1], cj[2]);
    dval[q] = D; m2v[q] = m2;
    lmax = fmaxf(lmax, D);
  }
  {
    float wm = wmaxf(lmax);
    if (lane == 0) sm.smax[wid] = wm;
  }
  __syncthreads();   // hist zeroed + smax ready
  const float Dmax = fmaxf(fmaxf(sm.smax[0], sm.smax[1]), fmaxf(sm.smax[2], sm.smax[3]));

  unsigned kb[8];
#pragma unroll
  for (int q = 0; q < 8; ++q) {
    float Dadj = dval[q] + (1.0f - m2v[q]) * Dmax;
    kb[q] = __float_as_uint(Dadj);      // positive float: bits monotone in value
  }
#pragma unroll
  for (int q = 0; q < 8; ++q) atomicAdd(&sm.u.s.hist[kb[q] >> 23], 1u);
  __syncthreads();

  // --- level-1 scan: find exponent-byte bin containing rank 30 ---
  unsigned c = sm.u.s.hist[tid];
  sm.u.s.hist[tid] = 0;                 // re-zero own slot for level 2
  unsigned v = c;
#pragma unroll
  for (int off = 1; off < 64; off <<= 1) {
    unsigned o = __shfl_up(v, off, 64);
    if (lane >= off) v += o;
  }
  if (lane == 63) sm.u.s.wsum[wid] = v;
  __syncthreads();
  {
    unsigned base = 0;
    if (wid > 0) base += sm.u.s.wsum[0];
    if (wid > 1) base += sm.u.s.wsum[1];
    if (wid > 2) base += sm.u.s.wsum[2];
    unsigned incl = v + base, excl = incl - c;
    if (excl <= 29u && incl >= 30u) { sm.u.s.T1 = (unsigned)tid; sm.u.s.r0 = excl; }
  }
  __syncthreads();
  const unsigned T1 = sm.u.s.T1, r0 = sm.u.s.r0;

  // --- level-2 histogram on mantissa-top byte within bin T1 ---
#pragma unroll
  for (int q = 0; q < 8; ++q)
    if ((kb[q] >> 23) == T1) atomicAdd(&sm.u.s.hist[(kb[q] >> 15) & 0xFFu], 1u);
  __syncthreads();
  c = sm.u.s.hist[tid];
  v = c;
#pragma unroll
  for (int off = 1; off < 64; off <<= 1) {
    unsigned o = __shfl_up(v, off, 64);
    if (lane >= off) v += o;
  }
  if (lane == 63) sm.u.s.wsum[wid] = v;
  __syncthreads();
  {
    unsigned base = 0;
    if (wid > 0) base += sm.u.s.wsum[0];
    if (wid > 1) base += sm.u.s.wsum[1];
    if (wid > 2) base += sm.u.s.wsum[2];
    unsigned incl = v + base, excl = incl - c;
    unsigned Kp = 30u - r0;
    if (excl < Kp && incl >= Kp) sm.u.s.Pthr = (T1 << 8) | (unsigned)tid;
  }
  __syncthreads();
  const unsigned Pthr = sm.u.s.Pthr;

  // --- compaction: survivors have 17-bit prefix <= Pthr ---
#pragma unroll
  for (int q = 0; q < 8; ++q) {
    unsigned P = kb[q] >> 15;
    if (P <= Pthr) {
      unsigned pos = atomicAdd(&sm.u.s.cnt, 1u);
      if (pos < CAP) {
        int j = (wid << 9) | (q << 6) | lane;
        sm.u.s.list[pos] = (((unsigned long long)kb[q]) << 32) | (unsigned)j;
      }
    }
  }
  __syncthreads();

  // --- exact rank-sort of survivors (keys unique: idx in low bits) ---
  {
    unsigned M = sm.u.s.cnt; if (M > CAP) M = CAP;
    if (tid < (int)M) {
      unsigned long long key = sm.u.s.list[tid];
      int rank = 0;
      for (unsigned s = 0; s < M; ++s) rank += (int)(sm.u.s.list[s] < key);
      if (rank < KNB) sm.selk[rank] = key;
    }
  }
  __syncthreads();

  // ---------------- phase 2a: gather neighbor atoms / buckets + write E_idx ----------------
  if (tid < KNB * 5) {
    int k = tid / 5, a = tid - 5 * k;
    int j = (int)(sm.selk[k] & 0xffffffffull);
    const float* base = X + (size_t)(b * LVAL + j) * 15;
    float o0, o1, o2;
    get_atom(base, a, o0, o1, o2);
    sm.u.p.natoms[(k * 5 + a) * 3 + 0] = o0;
    sm.u.p.natoms[(k * 5 + a) * 3 + 1] = o1;
    sm.u.p.natoms[(k * 5 + a) * 3 + 2] = o2;
  } else if (tid < KNB * 5 + 5) {
    int a = tid - KNB * 5;
    const float* base = X + (size_t)row * 15;
    float o0, o1, o2;
    get_atom(base, a, o0, o1, o2);
    sm.u.p.satoms[a * 3 + 0] = o0;
    sm.u.p.satoms[a * 3 + 1] = o1;
    sm.u.p.satoms[a * 3 + 2] = o2;
  }
  if (tid < KNB) {
    unsigned long long k64 = sm.selk[tid];
    int j = (int)(k64 & 0xffffffffull);
    int off = ridx[row] - ridx[b * LVAL + j];
    int same = (chain[row] == chain[b * LVAL + j]) ? 1 : 0;
    int d = same ? min(max(off + 32, 0), 64) : 65;
    sm.u.p.dk[tid] = d;
    sm.u.p.Dn[tid] = __uint_as_float((unsigned)(k64 >> 32));
    outI[(size_t)row * KNB + tid] = (float)(unsigned)j;
  }
  __syncthreads();

  // ---------------- phase 2b+2c fused: pair distance -> 16 RBF features (bf16) ----------------
  // feature layout per edge k: [0..15] pos, [16..31] rbf(Dn), [32+16p .. 47+16p] rbf(pair p)
  for (int idx = tid; idx < KNB * 25; idx += 256) {
    int k = idx / 25, s = idx - 25 * k;
    float D;
    if (s == 0) {
      D = sm.u.p.Dn[k];
    } else {
      const float* A = &sm.u.p.satoms[c_PI[s - 1] * 3];
      const float* Bq = &sm.u.p.natoms[(k * 5 + c_PJ[s - 1]) * 3];
      D = ca_dist(A[0], A[1], A[2], Bq[0], Bq[1], Bq[2]);
    }
    bf16x8 o0, o1;
#pragma unroll
    for (int r = 0; r < 8; ++r) {
      float t = (D - (2.0f + (4.0f / 3.0f) * (float)r)) * 0.8f;
      o0[r] = (__bf16)__expf(-(t * t));
    }
#pragma unroll
    for (int r = 8; r < 16; ++r) {
      float t = (D - (2.0f + (4.0f / 3.0f) * (float)r)) * 0.8f;
      o1[r - 8] = (__bf16)__expf(-(t * t));
    }
    __bf16* dst = &sm.a.feat[k * FPAD + 16 + s * 16];
    *(bf16x8*)dst = o0;
    *(bf16x8*)(dst + 8) = o1;
  }
  for (int idx = tid; idx < KNB * 16; idx += 256) {   // pos features
    int k = idx >> 4, f = idx & 15;
    sm.a.feat[k * FPAD + f] = (__bf16)(posW[f * NPOS + sm.u.p.dk[k]] + posb[f]);
  }
  {                                                   // zero pad rows 30,31 (1696 B)
    int4 z; z.x = 0; z.y = 0; z.z = 0; z.w = 0;
    if (tid < 106) ((int4*)&sm.a.feat[KNB * FPAD])[tid] = z;
  }
  __syncthreads();

  // ---------------- phase 3: MFMA GEMM  (32 x 416) @ (416 x 128) ----------------
  const int llo = lane & 15, lhi = lane >> 4;
  f32x4 acc00 = {0.f, 0.f, 0.f, 0.f}, acc01 = {0.f, 0.f, 0.f, 0.f};
  f32x4 acc10 = {0.f, 0.f, 0.f, 0.f}, acc11 = {0.f, 0.f, 0.f, 0.f};
  const __bf16* fbase0 = &sm.a.feat[llo * FPAD + lhi * 8];
  const __bf16* fbase1 = fbase0 + 16 * FPAD;
  const bf16x8* WFp = ((const bf16x8*)wf) + (2 * wid) * 64 + lane;
#pragma unroll
  for (int s = 0; s < 13; ++s) {
    bf16x8 a0 = *(const bf16x8*)(fbase0 + s * 32);
    bf16x8 a1 = *(const bf16x8*)(fbase1 + s * 32);
    bf16x8 b0 = WFp[s * 512];
    bf16x8 b1 = WFp[s * 512 + 64];
    acc00 = __builtin_amdgcn_mfma_f32_16x16x32_bf16(a0, b0, acc00, 0, 0, 0);
    acc01 = __builtin_amdgcn_mfma_f32_16x16x32_bf16(a0, b1, acc01, 0, 0, 0);
    acc10 = __builtin_amdgcn_mfma_f32_16x16x32_bf16(a1, b0, acc10, 0, 0, 0);
    acc11 = __builtin_amdgcn_mfma_f32_16x16x32_bf16(a1, b1, acc11, 0, 0, 0);
  }
  __syncthreads();   // feat (union w/ epre) fully read before epilogue writes
  // epilogue: C/D layout col=lane&15, row=(lane>>4)*4+reg ; rows 30,31 are zeros, kept
  {
    int cb0 = (2 * wid) * 16 + llo, cb1 = cb0 + 16;
#pragma unroll
    for (int j = 0; j < 4; ++j) {
      int m0 = lhi * 4 + j;
      int m1 = 16 + m0;
      sm.a.epre[m0 * 132 + cb0] = acc00[j];
      sm.a.epre[m0 * 132 + cb1] = acc01[j];
      sm.a.epre[m1 * 132 + cb0] = acc10[j];
      sm.a.epre[m1 * 132 + cb1] = acc11[j];
    }
  }
  __syncthreads();

  // ---------------- phase 4: LayerNorm via width-8 shuffles + fused store ----------------
  {
    int m = tid >> 3, sub = tid & 7;            // threads 8m..8m+7 own row m (same wave)
    const f32x4* rp = (const f32x4*)&sm.a.epre[m * 132 + sub * 16];
    f32x4 v0 = rp[0], v1 = rp[1], v2 = rp[2], v3 = rp[3];
    float s1 = ((v0[0] + v0[1]) + (v0[2] + v0[3])) + ((v1[0] + v1[1]) + (v1[2] + v1[3]))
             + ((v2[0] + v2[1]) + (v2[2] + v2[3])) + ((v3[0] + v3[1]) + (v3[2] + v3[3]));
    s1 += __shfl_xor(s1, 1, 64);
    s1 += __shfl_xor(s1, 2, 64);
    s1 += __shfl_xor(s1, 4, 64);
    float mu = s1 * (1.0f / 128.0f);
    float s2 = 0.f;
#pragma unroll
    for (int c2 = 0; c2 < 4; ++c2) { float d = v0[c2] - mu; s2 += d * d; }
#pragma unroll
    for (int c2 = 0; c2 < 4; ++c2) { float d = v1[c2] - mu; s2 += d * d; }
#pragma unroll
    for (int c2 = 0; c2 < 4; ++c2) { float d = v2[c2] - mu; s2 += d * d; }
#pragma unroll
    for (int c2 = 0; c2 < 4; ++c2) { float d = v3[c2] - mu; s2 += d * d; }
    s2 += __shfl_xor(s2, 1, 64);
    s2 += __shfl_xor(s2, 2, 64);
    s2 += __shfl_xor(s2, 4, 64);
    float rstd = rsqrtf(s2 * (1.0f / 128.0f) + 1e-5f);
    if (m < KNB) {
      const f32x4* gp = (const f32x4*)(lng + sub * 16);
      const f32x4* bp = (const f32x4*)(lnb + sub * 16);
      f32x4* op = (f32x4*)(outE + (size_t)row * KNB * NOUT + m * NOUT + sub * 16);
      f32x4 g0 = gp[0], g1 = gp[1], g2 = gp[2], g3 = gp[3];
      f32x4 b0 = bp[0], b1 = bp[1], b2 = bp[2], b3 = bp[3];
      f32x4 o0, o1, o2, o3;
#pragma unroll
      for (int c2 = 0; c2 < 4; ++c2) o0[c2] = (v0[c2] - mu) * rstd * g0[c2] + b0[c2];
#pragma unroll
      for (int c2 = 0; c2 < 4; ++c2) o1[c2] = (v1[c2] - mu) * rstd * g1[c2] + b1[c2];
#pragma unroll
      for (int c2 = 0; c2 < 4; ++c2) o2[c2] = (v2[c2] - mu) * rstd * g2[c2] + b2[c2];
#pragma unroll
      for (int c2 = 0; c2 < 4; ++c2) o3[c2] = (v3[c2] - mu) * rstd * g3[c2] + b3[c2];
      op[0] = o0; op[1] = o1; op[2] = o2; op[3] = o3;
    }
  }
}

extern "C" void kernel_launch(void* const* d_in, const int* in_sizes, int n_in,
                              void* d_out, int out_size, void* d_ws, size_t ws_size,
                              hipStream_t stream) {
  const float* X = (const float*)d_in[0];
  const float* mask = (const float*)d_in[1];
  const int* ridx = (const int*)d_in[2];
  const int* chain = (const int*)d_in[3];
  const float* posW = (const float*)d_in[4];
  const float* posb = (const float*)d_in[5];
  const float* edgeW = (const float*)d_in[6];
  const float* lng = (const float*)d_in[7];
  const float* lnb = (const float*)d_in[8];
  float* outE = (float*)d_out;
  float* outI = outE + (size_t)BVAL * LVAL * KNB * NOUT;
  __bf16* wf = (__bf16*)d_ws;

  hipLaunchKernelGGL(prep_w, dim3(208), dim3(256), 0, stream, edgeW, wf);
  hipLaunchKernelGGL(pf_kernel, dim3(BVAL * LVAL), dim3(256), 0, stream,
                     X, mask, ridx, chain, posW, posb, lng, lnb, wf, outE, outI);
}

// Round 4
// 228.598 us; speedup vs baseline: 2.1709x; 1.1279x over previous
//
#include <hip/hip_runtime.h>

#define LVAL 2048
#define KNB 30
#define NPOS 66
#define EDGE_IN 416
#define NOUT 128

typedef __bf16 bf16x8 __attribute__((ext_vector_type(8)));
typedef float f32x4 __attribute__((ext_vector_type(4)));

__device__ __constant__ unsigned char c_PI[24] = {0,2,3,4,1,1,1,1,0,0,0,4,4,3,0,2,3,4,2,3,4,2,3,2};
__device__ __constant__ unsigned char c_PJ[24] = {0,2,3,4,0,2,3,4,2,3,4,2,3,2,1,1,1,1,0,0,0,4,4,3};

// per-wave private scratch; NO cross-wave sharing anywhere -> zero __syncthreads
struct __align__(16) WaveMem {
  union {
    unsigned hist[256];        // radix-select histograms (levels 1+2, sequential)
    float Dtab[25 * 33];       // D table [group g][edge m], stride 33 kills 4-way bank conflicts
  } u;
  unsigned long long list[64]; // compacted survivors -> in-place rank-sorted top-30 keys
  float natoms[KNB * 15];      // neighbor atoms [k][a][xyz]
  float satoms[16];            // self atoms
  float Dn[32];                // D_neighbors (= chosen D_adjust values)
  int   dk[32];                // positional bucket
};
// sizeof ~5.95 KB -> 4 waves/block ~23.8 KB

// distance exactly as numpy: ((dx*dx)+(dy*dy))+(dz*dz), +1e-6, IEEE sqrt, no FMA contraction
__device__ inline float ca_dist(float ax, float ay, float az, float bx, float by, float bz) {
#pragma clang fp contract(off)
  float dx = bx - ax, dy = by - ay, dz = bz - az;
  float d2 = ((dx * dx) + (dy * dy)) + (dz * dz);
  return sqrtf(d2 + 1e-6f);
}

__device__ inline float wmaxf(float v) {
#pragma unroll
  for (int off = 32; off >= 1; off >>= 1) {
    float o = __shfl_xor(v, off, 64);
    v = fmaxf(v, o);
  }
  return v;
}

// find smallest bin with cumulative count >= K over 256 bins (4 bins/lane), intra-wave
__device__ inline void scan_find(const unsigned* hist, int lane, unsigned K,
                                 unsigned& bin, unsigned& below) {
  uint4 h = ((const uint4*)hist)[lane];
  unsigned p0 = h.x, p1 = p0 + h.y, p2 = p1 + h.z, p3 = p2 + h.w;
  unsigned v = p3;
#pragma unroll
  for (int off = 1; off < 64; off <<= 1) {
    unsigned o = __shfl_up(v, off, 64);
    if (lane >= off) v += o;
  }
  unsigned excl = v - p3;
  unsigned long long bal = __ballot(v >= K);
  int ff = __builtin_ctzll(bal);
  unsigned bi, r;
  if (excl + p0 >= K)      { bi = 0u; r = excl; }
  else if (excl + p1 >= K) { bi = 1u; r = excl + p0; }
  else if (excl + p2 >= K) { bi = 2u; r = excl + p1; }
  else                     { bi = 3u; r = excl + p2; }
  unsigned packed = ((4u * (unsigned)lane + bi) << 16) | (r & 0xffffu);
  packed = (unsigned)__shfl((int)packed, ff, 64);
  bin = packed >> 16; below = packed & 0xffffu;
}

// atom a (0=N,1=Ca,2=C,3=O(slot4),4=Cb) of residue at row-base pointer
__device__ inline void get_atom(const float* __restrict__ base, int a, float& o0, float& o1, float& o2) {
  if (a < 3) {
    o0 = base[a * 3 + 0]; o1 = base[a * 3 + 1]; o2 = base[a * 3 + 2];
  } else if (a == 3) {
    o0 = base[12]; o1 = base[13]; o2 = base[14];
  } else {
    float nx = base[0], ny = base[1], nz = base[2];
    float ax = base[3], ay = base[4], az = base[5];
    float cx = base[6], cy = base[7], cz = base[8];
    float bvx = ax - nx, bvy = ay - ny, bvz = az - nz;
    float cvx = cx - ax, cvy = cy - ay, cvz = cz - az;
    float avx = bvy * cvz - bvz * cvy;
    float avy = bvz * cvx - bvx * cvz;
    float avz = bvx * cvy - bvy * cvx;
    o0 = (-0.58273431f * avx + 0.56802827f * bvx) - 0.54067466f * cvx + ax;
    o1 = (-0.58273431f * avy + 0.56802827f * bvy) - 0.54067466f * cvy + ay;
    o2 = (-0.58273431f * avz + 0.56802827f * bvz) - 0.54067466f * cvz + az;
  }
}

// pre-swizzle edge_W (128x416 fp32) into bf16 B-fragment order:
// element id = ((s*8 + nt)*64 + lane)*8 + jj ; k = 32s + (lane>>4)*8 + jj ; n = nt*16 + (lane&15)
__global__ void prep_w(const float* __restrict__ W, __bf16* __restrict__ wf) {
  int id = blockIdx.x * 256 + threadIdx.x;
  if (id >= 13 * 8 * 64 * 8) return;
  int jj = id & 7, l = (id >> 3) & 63, nt = (id >> 9) & 7, s = id >> 12;
  int k = 32 * s + ((l >> 4) << 3) + jj;
  int n = nt * 16 + (l & 15);
  wf[id] = (__bf16)W[n * EDGE_IN + k];
}

__global__ __launch_bounds__(256, 4)
void pf_kernel(const float* __restrict__ X, const float* __restrict__ mask,
               const int* __restrict__ ridx, const int* __restrict__ chain,
               const float* __restrict__ posW, const float* __restrict__ posb,
               const float* __restrict__ lng, const float* __restrict__ lnb,
               const __bf16* __restrict__ wf,
               float* __restrict__ outE, float* __restrict__ outI) {
  __shared__ WaveMem smw[4];
  const int tid = threadIdx.x, lane = tid & 63, wid = tid >> 6;
  WaveMem& w = smw[wid];
  const int row = blockIdx.x * 4 + wid;     // one wave per row
  const int b = row >> 11;
  const float* __restrict__ Xb = X + (size_t)b * LVAL * 15;
  const float* __restrict__ mkb = mask + (size_t)b * LVAL;

  // ---------------- phase 1: distances (32 candidates/lane) ----------------
  const float cax = X[(row * 5 + 1) * 3 + 0];
  const float cay = X[(row * 5 + 1) * 3 + 1];
  const float caz = X[(row * 5 + 1) * 3 + 2];
  const float mi = mask[row];

  float Dv[32];
  unsigned mb = 0u;      // bit q set => candidate masked out
  float lmax = 0.f;
#pragma unroll 8
  for (int q = 0; q < 32; ++q) {
    int j = (q << 6) | lane;
    const float* cj = Xb + j * 15 + 3;
    float m2 = mi * mkb[j];
    float D = m2 * ca_dist(cax, cay, caz, cj[0], cj[1], cj[2]);
    Dv[q] = D;
    if (m2 == 0.f) mb |= (1u << q);
    lmax = fmaxf(lmax, D);
  }
  const float Dmax = wmaxf(lmax);
  const float fsc = 65280.0f / fmaxf(Dmax, 1e-30f);   // Dadj*fsc in [0,65280]

  // ---------------- radix select level 1 (value-uniform 256 bins) ----------------
  {
    int4 z = {0, 0, 0, 0};
    ((int4*)w.u.hist)[lane] = z;
  }
#pragma unroll 8
  for (int q = 0; q < 32; ++q) {
    float Dadj = Dv[q] + (((mb >> q) & 1u) ? Dmax : 0.f);
    Dv[q] = Dadj;                                     // Dv now holds D_adjust
    int fine = min((int)(Dadj * fsc), 65535);
    atomicAdd(&w.u.hist[fine >> 8], 1u);
  }
  unsigned T1, r0;
  scan_find(w.u.hist, lane, 30u, T1, r0);

  // ---------------- level 2 within bin T1 ----------------
  {
    int4 z = {0, 0, 0, 0};
    ((int4*)w.u.hist)[lane] = z;
  }
#pragma unroll 8
  for (int q = 0; q < 32; ++q) {
    int fine = min((int)(Dv[q] * fsc), 65535);
    if (((unsigned)fine >> 8) == T1) atomicAdd(&w.u.hist[fine & 255], 1u);
  }
  unsigned T2, r2dummy;
  scan_find(w.u.hist, lane, 30u - r0, T2, r2dummy);
  const unsigned Pthr = (T1 << 8) | T2;

  // ---------------- compaction (ballot, register-only counter) ----------------
  unsigned cum = 0;
  const unsigned long long lmaskbits = ((1ull << lane) - 1ull);
#pragma unroll 4
  for (int q = 0; q < 32; ++q) {
    int fine = min((int)(Dv[q] * fsc), 65535);
    bool pred = ((unsigned)fine <= Pthr);
    unsigned long long bal = __ballot(pred);
    if (pred) {
      unsigned pos = cum + (unsigned)__popcll(bal & lmaskbits);
      if (pos < 64u) {
        unsigned kb = __float_as_uint(Dv[q]);
        w.list[pos] = (((unsigned long long)kb) << 32) | (unsigned)((q << 6) | lane);
      }
    }
    cum += (unsigned)__popcll(bal);
  }
  const unsigned M = min(cum, 64u);

  // ---------------- exact rank-sort of survivors (keys unique via idx bits) ----------------
  unsigned long long mykey = (lane < (int)M) ? w.list[lane] : ~0ull;
  unsigned rank = 0;
  for (unsigned s = 0; s < M; ++s) {
    unsigned long long ks = __shfl(mykey, (int)s, 64);
    rank += (ks < mykey) ? 1u : 0u;
  }
  bool sel = (lane < (int)M) && (rank < KNB);
  if (sel) w.list[rank] = mykey;          // lockstep: all reads precede writes
  if (sel) {
    unsigned jj = (unsigned)(mykey & 0xffffffffull);
    w.Dn[rank] = __uint_as_float((unsigned)(mykey >> 32));
    int off = ridx[row] - ridx[b * LVAL + (int)jj];
    int same = (chain[row] == chain[b * LVAL + (int)jj]) ? 1 : 0;
    w.dk[rank] = same ? min(max(off + 32, 0), 64) : 65;
    outI[(size_t)row * KNB + rank] = (float)jj;
  }

  // ---------------- gather atoms ----------------
#pragma unroll
  for (int t = 0; t < 3; ++t) {
    int idx = lane + 64 * t;
    if (idx < KNB * 5) {
      int k = idx / 5, a = idx - 5 * k;
      unsigned jj = (unsigned)(w.list[k] & 0xffffffffull);
      const float* base = Xb + (size_t)jj * 15;
      float o0, o1, o2;
      get_atom(base, a, o0, o1, o2);
      w.natoms[k * 15 + a * 3 + 0] = o0;
      w.natoms[k * 15 + a * 3 + 1] = o1;
      w.natoms[k * 15 + a * 3 + 2] = o2;
    } else if (idx < KNB * 5 + 5) {
      int a = idx - KNB * 5;
      float o0, o1, o2;
      get_atom(X + (size_t)row * 15, a, o0, o1, o2);
      w.satoms[a * 3 + 0] = o0;
      w.satoms[a * 3 + 1] = o1;
      w.satoms[a * 3 + 2] = o2;
    }
  }

  // ---------------- distance table: Dtab[0][m]=Dn, Dtab[1+p][m]=pair p ----------------
  if (lane < 32) w.u.Dtab[lane] = w.Dn[lane];   // hist dead; union reuse
#pragma unroll
  for (int t = 0; t < 12; ++t) {
    int idx = lane + 64 * t;
    if (idx < 24 * KNB) {
      int p = idx / KNB, m = idx - KNB * p;
      const float* A = &w.satoms[c_PI[p] * 3];
      const float* Bq = &w.natoms[m * 15 + c_PJ[p] * 3];
      w.u.Dtab[(p + 1) * 33 + m] = ca_dist(A[0], A[1], A[2], Bq[0], Bq[1], Bq[2]);
    }
  }

  // ---------------- GEMM: A-frags built in registers, 208 MFMAs/wave ----------------
  const int llo = lane & 15, lhi = lane >> 4;
  f32x4 acc[2][8];
#pragma unroll
  for (int h = 0; h < 2; ++h)
#pragma unroll
    for (int nt = 0; nt < 8; ++nt) { acc[h][nt][0] = 0.f; acc[h][nt][1] = 0.f; acc[h][nt][2] = 0.f; acc[h][nt][3] = 0.f; }

  const bf16x8* WFp = ((const bf16x8*)wf) + lane;   // + (s*8+nt)*64
  const bool m1ok = (llo < 14);                      // edge llo+16 < 30 ?

#pragma unroll
  for (int s = 0; s < 13; ++s) {
    bf16x8 a0, a1;
    int f0 = s * 32 + lhi * 8;
    if (f0 < 16) {
      // positional-embedding features f0..f0+7
      int d0 = w.dk[llo];
      int d1 = m1ok ? w.dk[llo + 16] : 0;
#pragma unroll
      for (int jx = 0; jx < 8; ++jx) {
        int f = f0 + jx;
        float pb = posb[f];
        a0[jx] = (__bf16)(posW[f * NPOS + d0] + pb);
        a1[jx] = m1ok ? (__bf16)(posW[f * NPOS + d1] + pb) : (__bf16)0.f;
      }
    } else {
      int gi = (f0 - 16) >> 4;
      int rbase = (f0 - 16) & 15;                    // 0 or 8
      float D0 = w.u.Dtab[gi * 33 + llo];
      float D1 = m1ok ? w.u.Dtab[gi * 33 + llo + 16] : 2.f;
      float mu0 = 2.0f + (4.0f / 3.0f) * (float)rbase;
#pragma unroll
      for (int jx = 0; jx < 8; ++jx) {
        float mur = mu0 + (4.0f / 3.0f) * (float)jx;
        float t0 = (D0 - mur) * 0.8f;
        float t1 = (D1 - mur) * 0.8f;
        a0[jx] = (__bf16)__expf(-(t0 * t0));
        a1[jx] = m1ok ? (__bf16)__expf(-(t1 * t1)) : (__bf16)0.f;
      }
    }
    const bf16x8* wrow = WFp + s * 512;
#pragma unroll
    for (int nt = 0; nt < 8; ++nt) {
      bf16x8 bb = wrow[nt * 64];
      acc[0][nt] = __builtin_amdgcn_mfma_f32_16x16x32_bf16(a0, bb, acc[0][nt], 0, 0, 0);
      acc[1][nt] = __builtin_amdgcn_mfma_f32_16x16x32_bf16(a1, bb, acc[1][nt], 0, 0, 0);
    }
  }

  // ---------------- LayerNorm in registers + store ----------------
  float gv[8], bv[8];
#pragma unroll
  for (int nt = 0; nt < 8; ++nt) { gv[nt] = lng[nt * 16 + llo]; bv[nt] = lnb[nt * 16 + llo]; }
  float* __restrict__ oRow = outE + (size_t)row * KNB * NOUT;
#pragma unroll
  for (int h = 0; h < 2; ++h) {
#pragma unroll
    for (int r = 0; r < 4; ++r) {
      float s1 = 0.f;
#pragma unroll
      for (int nt = 0; nt < 8; ++nt) s1 += acc[h][nt][r];
      s1 += __shfl_xor(s1, 1, 64);
      s1 += __shfl_xor(s1, 2, 64);
      s1 += __shfl_xor(s1, 4, 64);
      s1 += __shfl_xor(s1, 8, 64);
      float mu = s1 * (1.0f / 128.0f);
      float s2 = 0.f;
#pragma unroll
      for (int nt = 0; nt < 8; ++nt) { float d = acc[h][nt][r] - mu; s2 += d * d; }
      s2 += __shfl_xor(s2, 1, 64);
      s2 += __shfl_xor(s2, 2, 64);
      s2 += __shfl_xor(s2, 4, 64);
      s2 += __shfl_xor(s2, 8, 64);
      float rstd = rsqrtf(s2 * (1.0f / 128.0f) + 1e-5f);
      int rowm = h * 16 + lhi * 4 + r;
      if (rowm < KNB) {
        float* op = oRow + (size_t)rowm * NOUT + llo;
#pragma unroll
        for (int nt = 0; nt < 8; ++nt)
          op[nt * 16] = (acc[h][nt][r] - mu) * rstd * gv[nt] + bv[nt];
      }
    }
  }
}

extern "C" void kernel_launch(void* const* d_in, const int* in_sizes, int n_in,
                              void* d_out, int out_size, void* d_ws, size_t ws_size,
                              hipStream_t stream) {
  const float* X = (const float*)d_in[0];
  const float* mask = (const float*)d_in[1];
  const int* ridx = (const int*)d_in[2];
  const int* chain = (const int*)d_in[3];
  const float* posW = (const float*)d_in[4];
  const float* posb = (const float*)d_in[5];
  const float* edgeW = (const float*)d_in[6];
  const float* lng = (const float*)d_in[7];
  const float* lnb = (const float*)d_in[8];
  float* outE = (float*)d_out;
  float* outI = outE + (size_t)4 * LVAL * KNB * NOUT;
  __bf16* wf = (__bf16*)d_ws;

  hipLaunchKernelGGL(prep_w, dim3(208), dim3(256), 0, stream, edgeW, wf);
  hipLaunchKernelGGL(pf_kernel, dim3(4 * LVAL / 4), dim3(256), 0, stream,
                     X, mask, ridx, chain, posW, posb, lng, lnb, wf, outE, outI);
}